// Round 14
// baseline (240.289 us; speedup 1.0000x reference)
//
#include <hip/hip_runtime.h>
#include <math.h>

// Problem constants (B=2, T=8, H=W=56, C=128, heads=8, hd=16, WS=7, nh=nw=8)
constexpr int H_   = 56;
constexpr int HW_  = 56 * 56;          // 3136
constexpr int NPIX = 8 * HW_;          // 25088 (per batch)
constexpr int SLAB = 128 * HW_ * 16;   // floats per q/k/v buffer
constexpr int WINSZ = 49 * 52;         // u32 per window tile (2548)
constexpr int BTSZ  = 64 * WINSZ;      // u32 per bt (163072)

typedef __attribute__((ext_vector_type(8))) short bf16x8;
typedef __attribute__((ext_vector_type(4))) float f32x4;
typedef __attribute__((ext_vector_type(4))) unsigned int u32x4;

__device__ __forceinline__ unsigned short f2bf(float x) {
  unsigned int u = __float_as_uint(x);
  unsigned int r = (u + 0x7fffu + ((u >> 16) & 1u)) >> 16;
  return (unsigned short)r;
}
__device__ __forceinline__ float bf2f(unsigned short h) {
  return __uint_as_float(((unsigned int)h) << 16);
}
__device__ __forceinline__ int clamp55(int v) {
  return v < 0 ? 0 : (v > 55 ? 55 : v);
}

// ---------------------------------------------------------------------------
// GEMM: unchanged (K1 qkv+l2norm+scatter, K3 proj).
// ---------------------------------------------------------------------------
template <int MODE>
__global__ __launch_bounds__(256, 3) void gemm128(
    const float* X, const float* __restrict__ Wt, const float* __restrict__ bias,
    float* __restrict__ Yq, float* __restrict__ Yk, float* __restrict__ Yv,
    float* Yout)
{
  __shared__ float xT[32][132];
  __shared__ float wT[32][132];
  const int tid = threadIdx.x;
  const int tx = tid & 15, ty = tid >> 4;
  const int mbase = blockIdx.x * 128;
  const int nt = (MODE == 0) ? (int)blockIdx.y : 0;
  const float* Wp = Wt + (size_t)nt * (128 * 128);

  float acc[8][8];
#pragma unroll
  for (int i = 0; i < 8; ++i)
#pragma unroll
    for (int j = 0; j < 8; ++j) acc[i][j] = 0.f;

  const int srow = tid >> 3;
  const int scol = (tid & 7) * 4;

  for (int kt = 0; kt < 4; ++kt) {
    if (kt) __syncthreads();
#pragma unroll
    for (int p = 0; p < 4; ++p) {
      int r = p * 32 + srow;
      float4 vx = *(const float4*)&X [(size_t)(mbase + r) * 128 + kt * 32 + scol];
      float4 vw = *(const float4*)&Wp[(size_t)r * 128 + kt * 32 + scol];
      xT[scol + 0][r] = vx.x; xT[scol + 1][r] = vx.y; xT[scol + 2][r] = vx.z; xT[scol + 3][r] = vx.w;
      wT[scol + 0][r] = vw.x; wT[scol + 1][r] = vw.y; wT[scol + 2][r] = vw.z; wT[scol + 3][r] = vw.w;
    }
    __syncthreads();
#pragma unroll 4
    for (int c = 0; c < 32; ++c) {
      float4 a0 = *(const float4*)&xT[c][tx * 4];
      float4 a1 = *(const float4*)&xT[c][64 + tx * 4];
      float4 b0 = *(const float4*)&wT[c][ty * 4];
      float4 b1 = *(const float4*)&wT[c][64 + ty * 4];
      float a[8] = {a0.x, a0.y, a0.z, a0.w, a1.x, a1.y, a1.z, a1.w};
      float b[8] = {b0.x, b0.y, b0.z, b0.w, b1.x, b1.y, b1.z, b1.w};
#pragma unroll
      for (int i = 0; i < 8; ++i)
#pragma unroll
        for (int j = 0; j < 8; ++j) acc[i][j] += a[i] * b[j];
    }
  }

  if (MODE == 0) {
    const int hq = ty >> 2;
    const int cq = (ty & 3) * 4;
    float* Ybase = (nt == 0) ? Yq : ((nt == 1) ? Yk : Yv);
#pragma unroll
    for (int i = 0; i < 8; ++i) {
      int gpix = mbase + ((i < 4) ? (tx * 4 + i) : (64 + tx * 4 + (i - 4)));
      int b = gpix / NPIX;
      int rem = gpix - b * NPIX;
      int t = rem / HW_;
      int s = rem - t * HW_;
      float s0 = acc[i][0]*acc[i][0] + acc[i][1]*acc[i][1] + acc[i][2]*acc[i][2] + acc[i][3]*acc[i][3];
      float s1 = acc[i][4]*acc[i][4] + acc[i][5]*acc[i][5] + acc[i][6]*acc[i][6] + acc[i][7]*acc[i][7];
      s0 += __shfl_xor(s0, 16); s0 += __shfl_xor(s0, 32);
      s1 += __shfl_xor(s1, 16); s1 += __shfl_xor(s1, 32);
      float r0 = 1.f, r1 = 1.f;
      if (nt < 2) {
        r0 = 1.f / fmaxf(sqrtf(s0), 1e-12f);
        r1 = 1.f / fmaxf(sqrtf(s1), 1e-12f);
      }
      int bt0 = (b * 8 + hq) * 8 + t;
      int bt1 = (b * 8 + hq + 4) * 8 + t;
      float* d0 = Ybase + ((size_t)bt0 * HW_ + s) * 16 + cq;
      float* d1 = Ybase + ((size_t)bt1 * HW_ + s) * 16 + cq;
      *(float4*)d0 = make_float4(acc[i][0]*r0, acc[i][1]*r0, acc[i][2]*r0, acc[i][3]*r0);
      *(float4*)d1 = make_float4(acc[i][4]*r1, acc[i][5]*r1, acc[i][6]*r1, acc[i][7]*r1);
    }
  } else {
    float4 bb0 = *(const float4*)&bias[ty * 4];
    float4 bb1 = *(const float4*)&bias[64 + ty * 4];
#pragma unroll
    for (int i = 0; i < 8; ++i) {
      int gpix = mbase + ((i < 4) ? (tx * 4 + i) : (64 + tx * 4 + (i - 4)));
      float* dst = Yout + (size_t)gpix * 128;
      *(float4*)&dst[ty * 4]      = make_float4(acc[i][0]+bb0.x, acc[i][1]+bb0.y, acc[i][2]+bb0.z, acc[i][3]+bb0.w);
      *(float4*)&dst[64 + ty * 4] = make_float4(acc[i][4]+bb1.x, acc[i][5]+bb1.y, acc[i][6]+bb1.z, acc[i][7]+bb1.w);
    }
  }
}

// ---------------------------------------------------------------------------
// K2a v2: dense correlation, WINDOW-MAJOR output [bt][win][49 rows][52 taps]
// (each window tile = one contiguous 10192B block).
//  - 2-row strips (h0=2*strip): each strip = 16 windows x 7 COMPLETE rows.
//  - lanes = (pixel, c4 channel-quarter): k reads direct from L2, fully
//    coalesced (16 consecutive pixels x full 64B line per inst); R12-style
//    8-load batches; DPP shfl_xor(1,2) reduce.
//  - taps staged in LDS st[52][113] (odd stride: conflict-free stores at
//    slot-stride 7 and reads at d-stride 113), then cooperative write-out in
//    contiguous 1456B runs per window -> coalesced (fixes the 3.4x write amp).
// ---------------------------------------------------------------------------
__global__ __launch_bounds__(256) void corr_dense(
    const float* __restrict__ qn, const float* __restrict__ kn,
    const float* __restrict__ pos1,
    unsigned int* __restrict__ cwpk, float* __restrict__ diib)
{
  __shared__ unsigned int st[52 * 113 + 112];   // 23.9 KB
  const int tid = threadIdx.x;
  const int c4 = tid & 3;
  const int pl = tid >> 2;             // pixel-lane 0..63
  const int bid = blockIdx.x;          // 3584 = 8 xcd * 16 g * 28 strips
  const int xcd = bid & 7;
  const int j = bid >> 3;              // 0..447
  const int g = j / 28;
  const int strip = j - g * 28;
  const int bt = xcd * 16 + g;
  const int h0 = strip * 2;
  const int a2 = h0 >> 3;
  const int wy0 = h0 & 7;
  const int win0 = wy0 * 8;
  const int t = bt & 7;
  const int btk = bt - t + ((t < 7) ? (t + 1) : 7);
  const float* qb = qn + (size_t)bt  * (HW_ * 16);
  const float* kb = kn + (size_t)btk * (HW_ * 16);

  // ---- compute: 2 passes x 64 pixel-lanes cover the strip's 112 pixels ----
#pragma unroll 1
  for (int pass = 0; pass < 2; ++pass) {
    const int p = pass * 64 + pl;
    const bool act = (p < 112);
    const int pc = act ? p : 0;
    const int py = (pc >= 56) ? 1 : 0;
    const int w = pc - py * 56;
    const int h = h0 + py;
    const int b3 = w >> 3, wx = w & 7;
    const int slot = (py * 8 + wx) * 7 + b3;
    const int row = a2 * 7 + b3;
    const float* p1r = pos1 + row * 49;
    const f32x4 qv = *(const f32x4*)(qb + (size_t)(h * 56 + w) * 16 + c4 * 4);
    const bool wr = act && (c4 == 0);
    float dii = 0.f;
#pragma unroll
    for (int dbase = 0; dbase < 48; dbase += 8) {
      f32x4 kv[8];
#pragma unroll
      for (int e = 0; e < 8; ++e) {
        const int d = dbase + e;                 // compile-time
        const int du = d / 7, dv = d % 7;        // compile-time
        const int hc = clamp55(h + du - 3);
        const int wc = clamp55(w + dv - 3);
        kv[e] = *(const f32x4*)(kb + (size_t)(hc * 56 + wc) * 16 + c4 * 4);
      }
#pragma unroll
      for (int e = 0; e < 8; ++e) {
        const int d = dbase + e;
        const int du = d / 7, dv = d % 7;
        const int hh = h + du - 3, ww = w + dv - 3;
        float pd = fmaf(qv.x, kv[e].x, fmaf(qv.y, kv[e].y, fmaf(qv.z, kv[e].z, qv.w * kv[e].w)));
        pd = ((unsigned)hh < 56u && (unsigned)ww < 56u) ? pd : 0.f;
        pd += __shfl_xor(pd, 1);
        pd += __shfl_xor(pd, 2);
        const float val = pd + p1r[d];
        dii += val * val;
        if (wr) {
          unsigned short hb = f2bf(val);
          unsigned short lb = f2bf(val - bf2f(hb));
          st[d * 113 + slot] = (unsigned)hb | ((unsigned)lb << 16);
        }
      }
    }
    { // d = 48 (du=6, dv=6)
      const int hh = h + 3, ww = w + 3;
      float pd = 0.f;
      if ((unsigned)hh < 56u && (unsigned)ww < 56u) {
        const f32x4 kv = *(const f32x4*)(kb + (size_t)(hh * 56 + ww) * 16 + c4 * 4);
        pd = fmaf(qv.x, kv.x, fmaf(qv.y, kv.y, fmaf(qv.z, kv.z, qv.w * kv.w)));
      }
      pd += __shfl_xor(pd, 1);
      pd += __shfl_xor(pd, 2);
      const float val = pd + p1r[48];
      dii += val * val;
      if (wr) {
        unsigned short hb = f2bf(val);
        unsigned short lb = f2bf(val - bf2f(hb));
        st[48 * 113 + slot] = (unsigned)hb | ((unsigned)lb << 16);
        st[49 * 113 + slot] = 0u;
        st[50 * 113 + slot] = 0u;
        st[51 * 113 + slot] = 0u;
        diib[bt * HW_ + h * 56 + w] = dii;
      }
    }
  }
  __syncthreads();

  // ---- coalesced write-out: 16 windows x contiguous 364-u32 (1456B) runs ----
  unsigned int* gw = cwpk + (size_t)bt * BTSZ + (size_t)win0 * WINSZ + a2 * 364;
#pragma unroll 1
  for (int f = tid; f < 5824; f += 256) {
    const int wl = f / 364;
    const int r = f - wl * 364;
    const int d = r % 52;
    const int b3 = r / 52;
    gw[wl * WINSZ + r] = st[d * 113 + wl * 7 + b3];
  }
}

// ---------------------------------------------------------------------------
// K2b v12: window attention; corr tile bulk-staged from contiguous
// window-major cwpk (10 x u32x4 insts, fully coalesced), fragments built from
// LDS (R9-proven path). Downstream identical to round 13.
// ---------------------------------------------------------------------------
__global__ __launch_bounds__(64, 2) void attn_mfma(
    const float* __restrict__ qn, const float* __restrict__ vv,
    const unsigned int* __restrict__ cwpk, const float* __restrict__ diib,
    const float* __restrict__ pos2, float* __restrict__ mid)
{
  __shared__ __align__(16) unsigned char smem[10840];
  unsigned int*   cwS  = (unsigned int*)smem;         // [49*52] u32 staged tile
  unsigned short* Pb   = (unsigned short*)smem;       // [49][72] bf16 (aliases cwS)
  float*          mi_s = (float*)(smem + 10240);      // [49]
  float*          scm  = (float*)(smem + 10440);      // [49]
  float*          sca  = (float*)(smem + 10640);      // [49]

  const int lane = threadIdx.x;
  const int lg = lane >> 4;       // mfma k-group
  const int lr = lane & 15;       // mfma row/col within tile
  const int bid = blockIdx.x;
  const int xcd = bid & 7;
  const int j = bid >> 3;
  const int bt = xcd * 16 + (j >> 6);
  const int win = j & 63;
  const int wy = win >> 3;
  const int wx = win & 7;
  const float* qb = qn + (size_t)bt * (HW_ * 16);
  const float* vb = vv + (size_t)bt * (HW_ * 16);
  const float* dib = diib + (size_t)bt * HW_;

  const bool rowok = (lane < 49);
  const int il = rowok ? lane : 48;

  // ---- bulk stage of this window's corr tile (contiguous 10192B) ----
  {
    const u32x4* src = (const u32x4*)(cwpk + (size_t)bt * BTSZ + (size_t)win * WINSZ);
    u32x4* dst = (u32x4*)cwS;
#pragma unroll
    for (int it = 0; it < 10; ++it) {
      int f = it * 64 + lane;
      if (f < 637) dst[f] = src[f];
    }
  }

  // ---- V loads early (raw f32, packed later) ----
  float xv[2][8];
#pragma unroll
  for (int ks = 0; ks < 2; ++ks) {
#pragma unroll
    for (int e = 0; e < 8; ++e) {
      int k = ks * 32 + lg * 8 + e;
      int kc2 = (k < 49) ? k : 0;
      int ka = (kc2 * 37) >> 8;
      int kb2 = kc2 - ka * 7;
      float x = vb[(size_t)((ka * 8 + wy) * 56 + (kb2 * 8 + wx)) * 16 + lr];
      xv[ks][e] = (k < 49) ? x : 0.f;
    }
  }

  // ---- dii + Cauchy-Schwarz shift (mi_s region is not aliased) ----
  {
    const int ia = (il * 37) >> 8;
    const int ib = il - ia * 7;
    float dii = dib[(ia * 8 + wy) * 56 + (ib * 8 + wx)];
    float md = dii;
#pragma unroll
    for (int o = 32; o >= 1; o >>= 1) md = fmaxf(md, __shfl_xor(md, o));
    if (rowok) mi_s[il] = sqrtf(dii * md);
  }
  asm volatile("s_waitcnt lgkmcnt(0)" ::: "memory");  // stage + mi stores retired

  // ---- A-fragments from staged LDS tile ----
  bf16x8 ah[4][2], al[4][2];
#pragma unroll
  for (int tt2 = 0; tt2 < 4; ++tt2) {
#pragma unroll
    for (int ks = 0; ks < 2; ++ks) {
      const int row = tt2 * 16 + lr;
      const int rowc = (row < 49) ? row : 0;
      const int cb = ks * 32 + lg * 8;
      const unsigned int* s2 = cwS + rowc * 52 + cb;
      unsigned int u0[8];
      *(u32x4*)&u0[0] = *(const u32x4*)s2;
      *(u32x4*)&u0[4] = *(const u32x4*)(s2 + 4);
      const bool rv = (row < 49);
#pragma unroll
      for (int e = 0; e < 8; ++e)
        if (!rv || (cb + e) >= 49) u0[e] = 0u;
      union { u32x4 uu; bf16x8 s; } Hh, Ll;
#pragma unroll
      for (int p = 0; p < 4; ++p) {
        Hh.uu[p] = (u0[2*p] & 0xffffu) | (u0[2*p+1] << 16);
        Ll.uu[p] = (u0[2*p] >> 16) | (u0[2*p+1] & 0xffff0000u);
      }
      ah[tt2][ks] = Hh.s;
      al[tt2][ks] = Ll.s;
    }
  }
  asm volatile("s_waitcnt lgkmcnt(0)" ::: "memory");  // cwS reads done; Pb may overwrite

  // ---- Sm mfma + exp drain into Pb ----
#pragma unroll
  for (int rt = 0; rt < 4; ++rt) {
    f32x4 C[4];
#pragma unroll
    for (int ct = 0; ct < 4; ++ct) C[ct] = (f32x4)0.f;
#pragma unroll
    for (int ks = 0; ks < 2; ++ks) {
#pragma unroll
      for (int ct = 0; ct < 4; ++ct) {
        C[ct] = __builtin_amdgcn_mfma_f32_16x16x32_bf16(ah[rt][ks], ah[ct][ks], C[ct], 0, 0, 0);
        C[ct] = __builtin_amdgcn_mfma_f32_16x16x32_bf16(ah[rt][ks], al[ct][ks], C[ct], 0, 0, 0);
        C[ct] = __builtin_amdgcn_mfma_f32_16x16x32_bf16(al[rt][ks], ah[ct][ks], C[ct], 0, 0, 0);
      }
    }
#pragma unroll
    for (int reg = 0; reg < 4; ++reg) {
      int row = rt * 16 + lg * 4 + reg;
      float m = mi_s[(row < 49) ? row : 0];
#pragma unroll
      for (int ct = 0; ct < 4; ++ct) {
        float p = __expf(C[ct][reg] - m);
        if (row < 49) Pb[row * 72 + ct * 16 + lr] = f2bf(p);
      }
    }
  }
  asm volatile("" ::: "memory");

  // ---- motion row sums ----
  if (rowok) {
    const u32x4* pr = (const u32x4*)(Pb + il * 72);
    unsigned int uu[28];
#pragma unroll
    for (int w = 0; w < 7; ++w) *(u32x4*)&uu[4*w] = pr[w];
    float s = 0.f;
#pragma unroll
    for (int w = 0; w < 24; ++w)
      s += bf2f((unsigned short)(uu[w] & 0xffffu)) + bf2f((unsigned short)(uu[w] >> 16));
    s += bf2f((unsigned short)(uu[24] & 0xffffu));
    scm[il] = 0.5f / s;
  }

  // ---- pack V fragments (hi/lo) ----
  bf16x8 vfh[2], vfl[2];
#pragma unroll
  for (int ks = 0; ks < 2; ++ks) {
    union { u32x4 u; bf16x8 s; } Hh, Ll;
#pragma unroll
    for (int p = 0; p < 4; ++p) {
      unsigned short h0 = f2bf(xv[ks][2*p]);
      unsigned short h1 = f2bf(xv[ks][2*p+1]);
      unsigned short l0 = f2bf(xv[ks][2*p]   - bf2f(h0));
      unsigned short l1 = f2bf(xv[ks][2*p+1] - bf2f(h1));
      Hh.u[p] = (unsigned int)h0 | ((unsigned int)h1 << 16);
      Ll.u[p] = (unsigned int)l0 | ((unsigned int)l1 << 16);
    }
    vfh[ks] = Hh.s;
    vfl[ks] = Ll.s;
  }

  // ---- motion PV ----
  f32x4 om[4];
#pragma unroll
  for (int rt = 0; rt < 4; ++rt) om[rt] = (f32x4)0.f;
#pragma unroll
  for (int ks = 0; ks < 2; ++ks) {
#pragma unroll
    for (int rt = 0; rt < 4; ++rt) {
      int row = rt * 16 + lr;
      int rowc = (row < 49) ? row : 0;
      bf16x8 pa = *(const bf16x8*)(Pb + rowc * 72 + ks * 32 + lg * 8);
      om[rt] = __builtin_amdgcn_mfma_f32_16x16x32_bf16(pa, vfh[ks], om[rt], 0, 0, 0);
      om[rt] = __builtin_amdgcn_mfma_f32_16x16x32_bf16(pa, vfl[ks], om[rt], 0, 0, 0);
    }
  }
  asm volatile("s_waitcnt lgkmcnt(0)" ::: "memory");  // motion Pb reads done before app overwrite

  // ---- appearance: qf fragments direct from global q + pos2 ----
  bf16x8 qf[4];
#pragma unroll
  for (int half = 0; half < 2; ++half) {
    f32x4 qa_[2], qb_[2], pa_[2], pb_[2];
#pragma unroll
    for (int u = 0; u < 2; ++u) {
      const int tt2 = half * 2 + u;
      int row = tt2 * 16 + lr;
      int rowc = (row < 49) ? row : 0;
      int a2 = (rowc * 37) >> 8;
      int b3 = rowc - a2 * 7;
      const int co = (lg & 1) * 8;
      const float* qsrc = qb + (size_t)((a2 * 8 + wy) * 56 + (b3 * 8 + wx)) * 16 + co;
      qa_[u] = *(const f32x4*)qsrc;
      qb_[u] = *(const f32x4*)(qsrc + 4);
      const float* p2 = pos2 + rowc * 16 + co;
      pa_[u] = *(const f32x4*)p2;
      pb_[u] = *(const f32x4*)(p2 + 4);
    }
#pragma unroll
    for (int u = 0; u < 2; ++u) {
      const int tt2 = half * 2 + u;
      int row = tt2 * 16 + lr;
      f32x4 w0 = qa_[u] + pa_[u], w1 = qb_[u] + pb_[u];
      float ws[8] = {w0.x, w0.y, w0.z, w0.w, w1.x, w1.y, w1.z, w1.w};
      const bool zv = (row >= 49) || (lg >= 2);
      union { u32x4 u4; bf16x8 s; } Q;
#pragma unroll
      for (int p = 0; p < 4; ++p) {
        unsigned int v = (unsigned)f2bf(ws[2*p]) | ((unsigned)f2bf(ws[2*p+1]) << 16);
        Q.u4[p] = zv ? 0u : v;
      }
      qf[tt2] = Q.s;
    }
  }

  // ---- appearance gram (K=16, plain bf16, shift 0) + exp drain ----
#pragma unroll
  for (int rt = 0; rt < 4; ++rt) {
    f32x4 Ca[4];
#pragma unroll
    for (int ct = 0; ct < 4; ++ct) Ca[ct] = (f32x4)0.f;
#pragma unroll
    for (int ct = 0; ct < 4; ++ct)
      Ca[ct] = __builtin_amdgcn_mfma_f32_16x16x32_bf16(qf[rt], qf[ct], Ca[ct], 0, 0, 0);
#pragma unroll
    for (int reg = 0; reg < 4; ++reg) {
      int row = rt * 16 + lg * 4 + reg;
#pragma unroll
      for (int ct = 0; ct < 4; ++ct) {
        float p = __expf(Ca[ct][reg]);
        if (row < 49) Pb[row * 72 + ct * 16 + lr] = f2bf(p);
      }
    }
  }
  asm volatile("" ::: "memory");

  // ---- appearance row sums ----
  if (rowok) {
    const u32x4* pr = (const u32x4*)(Pb + il * 72);
    unsigned int uu[28];
#pragma unroll
    for (int w = 0; w < 7; ++w) *(u32x4*)&uu[4*w] = pr[w];
    float s = 0.f;
#pragma unroll
    for (int w = 0; w < 24; ++w)
      s += bf2f((unsigned short)(uu[w] & 0xffffu)) + bf2f((unsigned short)(uu[w] >> 16));
    s += bf2f((unsigned short)(uu[24] & 0xffffu));
    sca[il] = 0.5f / s;
  }

  // ---- appearance PV ----
  f32x4 oa[4];
#pragma unroll
  for (int rt = 0; rt < 4; ++rt) oa[rt] = (f32x4)0.f;
#pragma unroll
  for (int ks = 0; ks < 2; ++ks) {
#pragma unroll
    for (int rt = 0; rt < 4; ++rt) {
      int row = rt * 16 + lr;
      int rowc = (row < 49) ? row : 0;
      bf16x8 pa = *(const bf16x8*)(Pb + rowc * 72 + ks * 32 + lg * 8);
      oa[rt] = __builtin_amdgcn_mfma_f32_16x16x32_bf16(pa, vfh[ks], oa[rt], 0, 0, 0);
      oa[rt] = __builtin_amdgcn_mfma_f32_16x16x32_bf16(pa, vfl[ks], oa[rt], 0, 0, 0);
    }
  }

  // ---- epilogue: out = om*scm[row] + oa*sca[row], write (B,N,C) layout ----
  {
    int b = bt >> 6, e = (bt >> 3) & 7, tt = bt & 7;
    size_t obase = ((size_t)(b * NPIX + tt * HW_)) * 128 + e * 16 + lr;
#pragma unroll
    for (int rt = 0; rt < 4; ++rt) {
#pragma unroll
      for (int reg = 0; reg < 4; ++reg) {
        int row = rt * 16 + lg * 4 + reg;
        if (row < 49) {
          float o = om[rt][reg] * scm[row] + oa[rt][reg] * sca[row];
          int a2 = (row * 37) >> 8;
          int b3 = row - a2 * 7;
          mid[obase + (size_t)((a2 * 8 + wy) * 56 + (b3 * 8 + wx)) * 128] = o;
        }
      }
    }
  }
}

// ---------------------------------------------------------------------------
extern "C" void kernel_launch(void* const* d_in, const int* in_sizes, int n_in,
                              void* d_out, int out_size, void* d_ws, size_t ws_size,
                              hipStream_t stream) {
  (void)in_sizes; (void)n_in; (void)out_size; (void)ws_size;
  const float* x      = (const float*)d_in[0];
  const float* qkv_w  = (const float*)d_in[1];
  const float* proj_w = (const float*)d_in[2];
  const float* proj_b = (const float*)d_in[3];
  const float* pos1   = (const float*)d_in[4];
  const float* pos2   = (const float*)d_in[5];
  float* out = (float*)d_out;

  float* qn = (float*)d_ws;                               // SLAB f32
  float* kc = qn + SLAB;                                  // SLAB f32
  float* vv = kc + SLAB;                                  // SLAB f32
  unsigned int* cwpk = (unsigned int*)(vv + SLAB);        // 128 * BTSZ u32
  float* diib = (float*)(cwpk + (size_t)128 * BTSZ + 64); // 128*HW_ f32

  // K1: QKV GEMM + per-head l2norm + scatter
  gemm128<0><<<dim3(392, 3), 256, 0, stream>>>(x, qkv_w, nullptr, qn, kc, vv, nullptr);
  // K2a: dense correlation, window-major coalesced output
  corr_dense<<<dim3(3584), 256, 0, stream>>>(qn, kc, pos1, cwpk, diib);
  // K2b: window attention from contiguous corr tiles
  attn_mfma<<<dim3(8192), 64, 0, stream>>>(qn, vv, cwpk, diib, pos2, out);
  // K3: output projection, in-place
  gemm128<1><<<dim3(392), 256, 0, stream>>>(out, proj_w, proj_b, nullptr, nullptr, nullptr, out);
}